// Round 1
// 240.459 us; speedup vs baseline: 1.0458x; 1.0458x over previous
//
#include <hip/hip_runtime.h>

#define HID 512
#define NH 8
#define HD 64
#define BATCH 4
#define SEQ 2048
#define MTOT (BATCH * SEQ)   // 8192

typedef unsigned short ushort_t;
typedef __bf16 bf16x8 __attribute__((ext_vector_type(8)));
typedef unsigned short ushort8v __attribute__((ext_vector_type(8)));
typedef unsigned short ushort4v __attribute__((ext_vector_type(4)));
typedef float floatx4 __attribute__((ext_vector_type(4)));

// Hardware f32->bf16 (RNE). Plain cast lets the compiler emit
// v_cvt_pk_bf16_f32 and fuse adjacent pairs (learn_hip m240: scalar cast
// beats hand-written inline-asm cvt_pk).
static __device__ __forceinline__ unsigned short f2bf(float f) {
  __bf16 b = (__bf16)f;
  return __builtin_bit_cast(unsigned short, b);
}
static __device__ __forceinline__ float bf2f(unsigned short s) {
  union { unsigned int u; float f; } c; c.u = ((unsigned int)s) << 16;
  return c.f;
}
static __device__ __forceinline__ bf16x8 asbf(ushort8v v) {
  return __builtin_bit_cast(bf16x8, v);
}
static __device__ __forceinline__ float max3f(float a, float b, float c) {
  return fmaxf(fmaxf(a, b), c);   // clang fuses to v_max3_f32
}

// 0.125 (1/sqrt(64)) * log2(e): softmax done in exp2 domain.
#define SC_LOG2E 0.18033688011112042f

// ---------- dtype detector (proven) ----------
__global__ void detect_dtype(const unsigned int* __restrict__ q, int* __restrict__ flag) {
  if (threadIdx.x == 0 && blockIdx.x == 0) {
    int hits = 0;
    for (int i = 0; i < 256; ++i) {
      unsigned e = (q[i] >> 7) & 0xff;
      hits += (e >= 110 && e <= 136) ? 1 : 0;
    }
    flag[0] = (hits >= 128) ? 1 : 0;
  }
}

// ---------- weight transpose+convert (proven) ----------
__global__ __launch_bounds__(256) void prep_w(
    const void* __restrict__ W0, const void* __restrict__ W1,
    const void* __restrict__ W2, const void* __restrict__ W3,
    ushort_t* __restrict__ T0, ushort_t* __restrict__ T1,
    ushort_t* __restrict__ T2, ushort_t* __restrict__ T3,
    const int* __restrict__ flag) {
  const int isbf = flag[0];
  const void* W; ushort_t* T;
  switch (blockIdx.y) {
    case 0: W = W0; T = T0; break;
    case 1: W = W1; T = T1; break;
    case 2: W = W2; T = T2; break;
    default: W = W3; T = T3; break;
  }
  int idx = blockIdx.x * 256 + threadIdx.x;
  int k = idx >> 9, n = idx & 511;
  ushort_t v = isbf ? ((const ushort_t*)W)[k * HID + n]
                    : f2bf(((const float*)W)[k * HID + n]);
  T[n * HID + k] = v;
}

// ---------- bias convert (proven) ----------
__global__ __launch_bounds__(256) void prep_b(
    const void* __restrict__ B0, const void* __restrict__ B1,
    const void* __restrict__ B2, const void* __restrict__ B3,
    float* __restrict__ biasF, const int* __restrict__ flag) {
  const int isbf = flag[0];
  int i = blockIdx.x * 256 + threadIdx.x;
  int t = i >> 9, j = i & 511;
  const void* B = (t == 0) ? B0 : (t == 1) ? B1 : (t == 2) ? B2 : B3;
  biasF[i] = isbf ? bf2f(((const ushort_t*)B)[j]) : ((const float*)B)[j];
}

// ---------- mask -> additive f32 bias (0 or -1e9), folded into softmax fma ----
__global__ __launch_bounds__(256) void prep_mask(
    const int* __restrict__ mask, float* __restrict__ mb) {
  int i = blockIdx.x * 256 + threadIdx.x;
  mb[i] = mask[i] ? 0.f : -1e9f;
}

// ---------- fused QKV LDS GEMM: z in {0,1,2} selects (X, Wt, bias, Y) by OFFSET ----
__global__ __launch_bounds__(256) void gemm_qkv(
    const void* __restrict__ X0, const void* __restrict__ X1, const void* __restrict__ X2,
    const ushort_t* __restrict__ WtBase, const float* __restrict__ biasBase,
    ushort_t* __restrict__ YBase, const int* __restrict__ flag) {
  const int isbf = flag[0];
  const int z = blockIdx.z;
  const void* X = (z == 0) ? X0 : (z == 1) ? X1 : X2;
  const ushort_t* Wt = WtBase + (size_t)z * HID * HID;
  const float* biasF = biasBase + (size_t)z * HID;
  ushort_t* Y = YBase + (size_t)z * MTOT * HID;

  const int tid = threadIdx.x;
  const int wid = tid >> 6, lane = tid & 63;
  const int id = lane & 15, quad = lane >> 4;
  const int wm = wid >> 1, wn = wid & 1;
  const int m0 = blockIdx.x * 64, n0 = blockIdx.y * 128;

  __shared__ ushort_t At[64 * 72];    // [m][k] stride 72
  __shared__ ushort_t Bt[128 * 72];   // [n][k] stride 72

  const int srow = tid >> 3;          // 0..31
  const int scol = (tid & 7) * 8;     // 0..56

  floatx4 acc[2][4];
#pragma unroll
  for (int i = 0; i < 2; ++i)
#pragma unroll
    for (int j = 0; j < 4; ++j) acc[i][j] = (floatx4){0.f, 0.f, 0.f, 0.f};

  for (int k0 = 0; k0 < HID; k0 += 64) {
    ushort8v aR[2], bR[4];
    if (isbf) {
      const ushort_t* ap = (const ushort_t*)X + (long)(m0 + srow) * HID + k0 + scol;
#pragma unroll
      for (int p = 0; p < 2; ++p) aR[p] = *(const ushort8v*)(ap + (long)p * 32 * HID);
    } else {
      const float* apf = (const float*)X + (long)(m0 + srow) * HID + k0 + scol;
#pragma unroll
      for (int p = 0; p < 2; ++p) {
        floatx4 f0 = *(const floatx4*)(apf + (long)p * 32 * HID);
        floatx4 f1 = *(const floatx4*)(apf + (long)p * 32 * HID + 4);
#pragma unroll
        for (int i = 0; i < 4; ++i) { aR[p][i] = f2bf(f0[i]); aR[p][4 + i] = f2bf(f1[i]); }
      }
    }
    {
      const ushort_t* bp = Wt + (long)(n0 + srow) * HID + k0 + scol;
#pragma unroll
      for (int p = 0; p < 4; ++p) bR[p] = *(const ushort8v*)(bp + (long)p * 32 * HID);
    }
    __syncthreads();   // previous iter's LDS reads complete
#pragma unroll
    for (int p = 0; p < 2; ++p) *(ushort8v*)(&At[(srow + 32 * p) * 72 + scol]) = aR[p];
#pragma unroll
    for (int p = 0; p < 4; ++p) *(ushort8v*)(&Bt[(srow + 32 * p) * 72 + scol]) = bR[p];
    __syncthreads();
#pragma unroll
    for (int kk = 0; kk < 64; kk += 32) {
      ushort8v af[2], bf4[4];
#pragma unroll
      for (int ms = 0; ms < 2; ++ms) af[ms] = *(const ushort8v*)(&At[(wm * 32 + ms * 16 + id) * 72 + kk + quad * 8]);
#pragma unroll
      for (int ns = 0; ns < 4; ++ns) bf4[ns] = *(const ushort8v*)(&Bt[(wn * 64 + ns * 16 + id) * 72 + kk + quad * 8]);
#pragma unroll
      for (int ms = 0; ms < 2; ++ms)
#pragma unroll
        for (int ns = 0; ns < 4; ++ns)
          acc[ms][ns] = __builtin_amdgcn_mfma_f32_16x16x32_bf16(asbf(af[ms]), asbf(bf4[ns]), acc[ms][ns], 0, 0, 0);
    }
  }
#pragma unroll
  for (int ns = 0; ns < 4; ++ns) {
    float bv = biasF[n0 + wn * 64 + ns * 16 + id];
    int col = n0 + wn * 64 + ns * 16 + id;
#pragma unroll
    for (int ms = 0; ms < 2; ++ms) {
      int row0 = m0 + wm * 32 + ms * 16 + quad * 4;
#pragma unroll
      for (int r = 0; r < 4; ++r)
        Y[(long)(row0 + r) * HID + col] = f2bf(acc[ms][ns][r] + bv);
    }
  }
}

// ---------- LDS-staged GEMM (output proj, proven structure) ----------
__global__ __launch_bounds__(256) void gemm_lds_out(
    const ushort_t* __restrict__ X, const ushort_t* __restrict__ Wt,
    const float* __restrict__ biasF, void* __restrict__ out,
    const int* __restrict__ flag) {
  const int isbf = flag[0];
  const int tid = threadIdx.x;
  const int wid = tid >> 6, lane = tid & 63;
  const int id = lane & 15, quad = lane >> 4;
  const int wm = wid >> 1, wn = wid & 1;
  const int m0 = blockIdx.x * 64, n0 = blockIdx.y * 128;

  __shared__ ushort_t At[64 * 72];
  __shared__ ushort_t Bt[128 * 72];

  const int srow = tid >> 3;
  const int scol = (tid & 7) * 8;

  floatx4 acc[2][4];
#pragma unroll
  for (int i = 0; i < 2; ++i)
#pragma unroll
    for (int j = 0; j < 4; ++j) acc[i][j] = (floatx4){0.f, 0.f, 0.f, 0.f};

  for (int k0 = 0; k0 < HID; k0 += 64) {
    ushort8v aR[2], bR[4];
    {
      const ushort_t* ap = X + (long)(m0 + srow) * HID + k0 + scol;
#pragma unroll
      for (int p = 0; p < 2; ++p) aR[p] = *(const ushort8v*)(ap + (long)p * 32 * HID);
      const ushort_t* bp = Wt + (long)(n0 + srow) * HID + k0 + scol;
#pragma unroll
      for (int p = 0; p < 4; ++p) bR[p] = *(const ushort8v*)(bp + (long)p * 32 * HID);
    }
    __syncthreads();
#pragma unroll
    for (int p = 0; p < 2; ++p) *(ushort8v*)(&At[(srow + 32 * p) * 72 + scol]) = aR[p];
#pragma unroll
    for (int p = 0; p < 4; ++p) *(ushort8v*)(&Bt[(srow + 32 * p) * 72 + scol]) = bR[p];
    __syncthreads();
#pragma unroll
    for (int kk = 0; kk < 64; kk += 32) {
      ushort8v af[2], bf4[4];
#pragma unroll
      for (int ms = 0; ms < 2; ++ms) af[ms] = *(const ushort8v*)(&At[(wm * 32 + ms * 16 + id) * 72 + kk + quad * 8]);
#pragma unroll
      for (int ns = 0; ns < 4; ++ns) bf4[ns] = *(const ushort8v*)(&Bt[(wn * 64 + ns * 16 + id) * 72 + kk + quad * 8]);
#pragma unroll
      for (int ms = 0; ms < 2; ++ms)
#pragma unroll
        for (int ns = 0; ns < 4; ++ns)
          acc[ms][ns] = __builtin_amdgcn_mfma_f32_16x16x32_bf16(asbf(af[ms]), asbf(bf4[ns]), acc[ms][ns], 0, 0, 0);
    }
  }
#pragma unroll
  for (int ns = 0; ns < 4; ++ns) {
    float bv = biasF[n0 + wn * 64 + ns * 16 + id];
    int col = n0 + wn * 64 + ns * 16 + id;
#pragma unroll
    for (int ms = 0; ms < 2; ++ms) {
      int row0 = m0 + wm * 32 + ms * 16 + quad * 4;
      if (isbf) {
        ushort_t* o = (ushort_t*)out;
#pragma unroll
        for (int r = 0; r < 4; ++r) o[(long)(row0 + r) * HID + col] = f2bf(acc[ms][ns][r] + bv);
      } else {
        float* o = (float*)out;
#pragma unroll
        for (int r = 0; r < 4; ++r) o[(long)(row0 + r) * HID + col] = acc[ms][ns][r] + bv;
      }
    }
  }
}

// ---------- flash attention — exp2-domain softmax, additive mask bias,
// hw bf16 casts, defer-max rescale (T13), register K/V prefetch (T14-lite),
// 2 barriers/tile (Pl is per-wave; mid barrier removed). ----------
__global__ __launch_bounds__(256) void flash_attn(
    const ushort_t* __restrict__ Q, const ushort_t* __restrict__ K,
    const ushort_t* __restrict__ V, const float* __restrict__ mb,
    ushort_t* __restrict__ ctx) {
  const int qblk = blockIdx.x, h = blockIdx.y, b = blockIdx.z;
  const int tid = threadIdx.x;
  const int wid = tid >> 6, lane = tid & 63;
  const int id = lane & 15, quad = lane >> 4;

  __shared__ ushort_t Kt[64 * 72];       // [key][d] stride 72
  __shared__ ushort_t Vt[64 * 72];       // [d][key] stride 72 (transposed)
  __shared__ ushort_t Pl[4][32 * 72];    // per-wave P as [q][key] stride 72

  const ushort_t* Qb = Q + (long)(b * SEQ + qblk * 128 + wid * 32) * HID + h * HD;
  const ushort_t* Kb = K + (long)(b * SEQ) * HID + h * HD;
  const ushort_t* Vb = V + (long)(b * SEQ) * HID + h * HD;
  const float* mrow = mb + b * SEQ;

  ushort8v qf[2][2];
#pragma unroll
  for (int qs = 0; qs < 2; ++qs)
#pragma unroll
    for (int kh = 0; kh < 2; ++kh)
      qf[qs][kh] = *(const ushort8v*)(Qb + (qs * 16 + id) * HID + kh * 32 + quad * 8);

  floatx4 o[4][2];
  float m_i[2] = {-1e30f, -1e30f}, l_i[2] = {0.f, 0.f};
#pragma unroll
  for (int dg = 0; dg < 4; ++dg) { o[dg][0] = (floatx4){0,0,0,0}; o[dg][1] = (floatx4){0,0,0,0}; }

  const int skey = tid >> 2;             // K staging: 0..63
  const int sdc  = (tid & 3) * 16;       // K staging: 0,16,32,48
  const int vkp  = (tid & 31) * 2;       // V staging: key pair 0..62
  const int vdc  = (tid >> 5) * 8;       // V staging: d col 0..56

  // prefetch tile 0 into registers
  ushort8v k0v, k1v, v0v, v1v;
  {
    const ushort_t* kpp = Kb + (long)skey * HID + sdc;
    k0v = *(const ushort8v*)(kpp);
    k1v = *(const ushort8v*)(kpp + 8);
    const ushort_t* vp0 = Vb + (long)vkp * HID + vdc;
    v0v = *(const ushort8v*)(vp0);
    v1v = *(const ushort8v*)(vp0 + HID);
  }

  for (int kb = 0; kb < SEQ / 64; ++kb) {
    // ---- write prefetched regs to LDS (K row-major, V transposed/packed) ----
    *(ushort8v*)(&Kt[skey * 72 + sdc])     = k0v;
    *(ushort8v*)(&Kt[skey * 72 + sdc + 8]) = k1v;
#pragma unroll
    for (int i = 0; i < 8; ++i) {
      unsigned int dw = (unsigned int)v0v[i] | ((unsigned int)v1v[i] << 16);
      *(unsigned int*)(&Vt[(vdc + i) * 72 + vkp]) = dw;
    }
    __syncthreads();

    // ---- issue next-tile global loads; latency hides under this tile's compute ----
    if (kb + 1 < SEQ / 64) {
      const ushort_t* kpp = Kb + (long)((kb + 1) * 64 + skey) * HID + sdc;
      k0v = *(const ushort8v*)(kpp);
      k1v = *(const ushort8v*)(kpp + 8);
      const ushort_t* vp0 = Vb + (long)((kb + 1) * 64 + vkp) * HID + vdc;
      v0v = *(const ushort8v*)(vp0);
      v1v = *(const ushort8v*)(vp0 + HID);
    }

    floatx4 st[2][4];
#pragma unroll
    for (int ks = 0; ks < 4; ++ks) {
      ushort8v kf0 = *(const ushort8v*)(&Kt[(ks * 16 + id) * 72 + quad * 8]);
      ushort8v kf1 = *(const ushort8v*)(&Kt[(ks * 16 + id) * 72 + 32 + quad * 8]);
#pragma unroll
      for (int qs = 0; qs < 2; ++qs) {
        floatx4 a = (floatx4){0,0,0,0};
        a = __builtin_amdgcn_mfma_f32_16x16x32_bf16(asbf(kf0), asbf(qf[qs][0]), a, 0, 0, 0);
        a = __builtin_amdgcn_mfma_f32_16x16x32_bf16(asbf(kf1), asbf(qf[qs][1]), a, 0, 0, 0);
        st[qs][ks] = a;
      }
    }
    // ---- scale (exp2 domain) + additive mask bias in one fma ----
#pragma unroll
    for (int ks = 0; ks < 4; ++ks) {
      floatx4 mbv = *(const floatx4*)(mrow + kb * 64 + ks * 16 + quad * 4);
#pragma unroll
      for (int r = 0; r < 4; ++r) {
        st[0][ks][r] = fmaf(st[0][ks][r], SC_LOG2E, mbv[r]);
        st[1][ks][r] = fmaf(st[1][ks][r], SC_LOG2E, mbv[r]);
      }
    }
#pragma unroll
    for (int qs = 0; qs < 2; ++qs) {
      float a0 = max3f(st[qs][0][0], st[qs][0][1], st[qs][0][2]);
      float a1 = max3f(st[qs][0][3], st[qs][1][0], st[qs][1][1]);
      float a2 = max3f(st[qs][1][2], st[qs][1][3], st[qs][2][0]);
      float a3 = max3f(st[qs][2][1], st[qs][2][2], st[qs][2][3]);
      float a4 = max3f(st[qs][3][0], st[qs][3][1], st[qs][3][2]);
      float mx = max3f(a0, a1, st[qs][3][3]);
      float mz = max3f(a2, a3, a4);
      mx = fmaxf(mx, mz);
      mx = fmaxf(mx, __shfl_xor(mx, 16));
      mx = fmaxf(mx, __shfl_xor(mx, 32));
      // defer-max (T13): skip O/l rescale while max growth <= 8 (log2 units);
      // P bounded by 2^8, safe in bf16/f32 accumulation.
      if (!__all(mx - m_i[qs] <= 8.f)) {
        float mnew = fmaxf(m_i[qs], mx);
        float alpha = exp2f(m_i[qs] - mnew);
        m_i[qs] = mnew;
        l_i[qs] *= alpha;
#pragma unroll
        for (int dg = 0; dg < 4; ++dg) o[dg][qs] *= alpha;
      }
      float mcur = m_i[qs];
      float rs = 0.f;
#pragma unroll
      for (int ks = 0; ks < 4; ++ks) {
        ushort4v pk;
#pragma unroll
        for (int r = 0; r < 4; ++r) {
          float p = exp2f(st[qs][ks][r] - mcur);
          rs += p;
          pk[r] = f2bf(p);
        }
        *(ushort4v*)(&Pl[wid][(qs * 16 + id) * 72 + ks * 16 + quad * 4]) = pk;
      }
      rs += __shfl_xor(rs, 16);
      rs += __shfl_xor(rs, 32);
      l_i[qs] += rs;
    }
    // Pl is per-wave (indexed by wid): no barrier needed before PV reads;
    // compiler inserts the intra-wave lgkmcnt wait.

#pragma unroll
    for (int kc = 0; kc < 2; ++kc) {
      ushort8v pf0 = *(const ushort8v*)(&Pl[wid][(0 * 16 + id) * 72 + kc * 32 + quad * 8]);
      ushort8v pf1 = *(const ushort8v*)(&Pl[wid][(1 * 16 + id) * 72 + kc * 32 + quad * 8]);
#pragma unroll
      for (int dg = 0; dg < 4; ++dg) {
        ushort8v vf = *(const ushort8v*)(&Vt[(dg * 16 + id) * 72 + kc * 32 + quad * 8]);
        o[dg][0] = __builtin_amdgcn_mfma_f32_16x16x32_bf16(asbf(vf), asbf(pf0), o[dg][0], 0, 0, 0);
        o[dg][1] = __builtin_amdgcn_mfma_f32_16x16x32_bf16(asbf(vf), asbf(pf1), o[dg][1], 0, 0, 0);
      }
    }
    __syncthreads();   // all waves done reading Kt/Vt before next-tile staging
  }

#pragma unroll
  for (int qs = 0; qs < 2; ++qs) {
    float inv = 1.0f / l_i[qs];
    long qrow = (long)(b * SEQ + qblk * 128 + wid * 32 + qs * 16 + id);
#pragma unroll
    for (int dg = 0; dg < 4; ++dg) {
      ushort4v pk;
#pragma unroll
      for (int r = 0; r < 4; ++r) pk[r] = f2bf(o[dg][qs][r] * inv);
      *(ushort4v*)(&ctx[qrow * HID + h * HD + dg * 16 + quad * 4]) = pk;
    }
  }
}

extern "C" void kernel_launch(void* const* d_in, const int* in_sizes, int n_in,
                              void* d_out, int out_size, void* d_ws, size_t ws_size,
                              hipStream_t stream) {
  const void* values = d_in[0];
  const void* keys   = d_in[1];
  const void* query  = d_in[2];
  const int*  mask   = (const int*)d_in[3];
  const void* Wq = d_in[4];  const void* bq = d_in[5];
  const void* Wk = d_in[6];  const void* bk = d_in[7];
  const void* Wv = d_in[8];  const void* bv = d_in[9];
  const void* Wo = d_in[10]; const void* bo = d_in[11];

  ushort_t* ws = (ushort_t*)d_ws;
  const size_t NEL = (size_t)MTOT * HID;
  ushort_t* Qp  = ws;                       // Qp/Kp/Vp contiguous (gemm_qkv offsets)
  ushort_t* Kp  = ws + NEL;
  ushort_t* Vp  = ws + 2 * NEL;
  ushort_t* Cp  = ws + 3 * NEL;
  ushort_t* WqT = ws + 4 * NEL;             // WqT/WkT/WvT contiguous
  ushort_t* WkT = WqT + (size_t)HID * HID;
  ushort_t* WvT = WkT + (size_t)HID * HID;
  ushort_t* WoT = WvT + (size_t)HID * HID;
  float* biasF  = (float*)(WoT + (size_t)HID * HID);   // q,k,v,o contiguous
  float* mbias  = biasF + 4 * HID;                     // BATCH*SEQ floats
  int* flag     = (int*)(mbias + (size_t)BATCH * SEQ);

  detect_dtype<<<1, 64, 0, stream>>>((const unsigned int*)query, flag);
  prep_w<<<dim3(1024, 4), 256, 0, stream>>>(Wq, Wk, Wv, Wo, WqT, WkT, WvT, WoT, flag);
  prep_b<<<8, 256, 0, stream>>>(bq, bk, bv, bo, biasF, flag);
  prep_mask<<<MTOT / 256, 256, 0, stream>>>(mask, mbias);

  // fused QKV: grid (128, 4, 3) = 1536 blocks (~5 blocks/CU, LDS-capped)
  gemm_qkv<<<dim3(MTOT / 64, HID / 128, 3), 256, 0, stream>>>(
      query, keys, values, WqT, biasF, Qp, flag);

  flash_attn<<<dim3(SEQ / 128, NH, BATCH), 256, 0, stream>>>(Qp, Kp, Vp, mbias, Cp);

  gemm_lds_out<<<dim3(MTOT / 64, HID / 128), 256, 0, stream>>>(
      Cp, WoT, biasF + 3 * HID, d_out, flag);
}

// Round 2
// 231.348 us; speedup vs baseline: 1.0870x; 1.0394x over previous
//
#include <hip/hip_runtime.h>

#define HID 512
#define NH 8
#define HD 64
#define BATCH 4
#define SEQ 2048
#define MTOT (BATCH * SEQ)   // 8192

typedef unsigned short ushort_t;
typedef __bf16 bf16x8 __attribute__((ext_vector_type(8)));
typedef unsigned short ushort8v __attribute__((ext_vector_type(8)));
typedef unsigned short ushort4v __attribute__((ext_vector_type(4)));
typedef float floatx4 __attribute__((ext_vector_type(4)));
typedef unsigned int uintx4 __attribute__((ext_vector_type(4)));

static __device__ __forceinline__ unsigned short f2bf(float f) {
  __bf16 b = (__bf16)f;                    // hw v_cvt_pk_bf16_f32 (RNE)
  return __builtin_bit_cast(unsigned short, b);
}
static __device__ __forceinline__ float bf2f(unsigned short s) {
  union { unsigned int u; float f; } c; c.u = ((unsigned int)s) << 16;
  return c.f;
}
static __device__ __forceinline__ bf16x8 asbf(ushort8v v) {
  return __builtin_bit_cast(bf16x8, v);
}
static __device__ __forceinline__ float max3f(float a, float b, float c) {
  return fmaxf(fmaxf(a, b), c);            // v_max3_f32
}
// raw v_exp_f32 (2^x); domain here is x <= 0 (post max-subtraction)
static __device__ __forceinline__ float fexp2(float x) {
  return __builtin_amdgcn_exp2f(x);
}
// async global->LDS, 16B per lane, linear dest (wave-uniform base + lane*16)
static __device__ __forceinline__ void gl_lds16(const ushort_t* g, ushort_t* l) {
  __builtin_amdgcn_global_load_lds(
      (const __attribute__((address_space(1))) void*)g,
      (__attribute__((address_space(3))) void*)l, 16, 0, 0);
}

// 0.125 (1/sqrt(64)) * log2(e): softmax in exp2 domain.
#define SC_LOG2E 0.18033688011112042f

// ---------- dtype detector (proven) ----------
__global__ void detect_dtype(const unsigned int* __restrict__ q, int* __restrict__ flag) {
  if (threadIdx.x == 0 && blockIdx.x == 0) {
    int hits = 0;
    for (int i = 0; i < 256; ++i) {
      unsigned e = (q[i] >> 7) & 0xff;
      hits += (e >= 110 && e <= 136) ? 1 : 0;
    }
    flag[0] = (hits >= 128) ? 1 : 0;
  }
}

// ---------- weight transpose+convert (proven) ----------
__global__ __launch_bounds__(256) void prep_w(
    const void* __restrict__ W0, const void* __restrict__ W1,
    const void* __restrict__ W2, const void* __restrict__ W3,
    ushort_t* __restrict__ T0, ushort_t* __restrict__ T1,
    ushort_t* __restrict__ T2, ushort_t* __restrict__ T3,
    const int* __restrict__ flag) {
  const int isbf = flag[0];
  const void* W; ushort_t* T;
  switch (blockIdx.y) {
    case 0: W = W0; T = T0; break;
    case 1: W = W1; T = T1; break;
    case 2: W = W2; T = T2; break;
    default: W = W3; T = T3; break;
  }
  int idx = blockIdx.x * 256 + threadIdx.x;
  int k = idx >> 9, n = idx & 511;
  ushort_t v = isbf ? ((const ushort_t*)W)[k * HID + n]
                    : f2bf(((const float*)W)[k * HID + n]);
  T[n * HID + k] = v;
}

// ---------- bias convert (proven) ----------
__global__ __launch_bounds__(256) void prep_b(
    const void* __restrict__ B0, const void* __restrict__ B1,
    const void* __restrict__ B2, const void* __restrict__ B3,
    float* __restrict__ biasF, const int* __restrict__ flag) {
  const int isbf = flag[0];
  int i = blockIdx.x * 256 + threadIdx.x;
  int t = i >> 9, j = i & 511;
  const void* B = (t == 0) ? B0 : (t == 1) ? B1 : (t == 2) ? B2 : B3;
  biasF[i] = isbf ? bf2f(((const ushort_t*)B)[j]) : ((const float*)B)[j];
}

// ---------- mask -> additive f32 bias (0 or -1e9) ----------
__global__ __launch_bounds__(256) void prep_mask(
    const int* __restrict__ mask, float* __restrict__ mb) {
  int i = blockIdx.x * 256 + threadIdx.x;
  mb[i] = mask[i] ? 0.f : -1e9f;
}

// ---------- X (query/keys/values) -> bf16, one pass ----------
// Kills the per-N-block f32 re-read + convert that gemm_qkv used to do 4x.
__global__ __launch_bounds__(256) void prep_x(
    const void* __restrict__ X0, const void* __restrict__ X1,
    const void* __restrict__ X2, ushort_t* __restrict__ Xb,
    const int* __restrict__ flag) {
  const int isbf = flag[0];
  const int z = blockIdx.y;
  const void* X = (z == 0) ? X0 : (z == 1) ? X1 : X2;
  long i = (long)(blockIdx.x * 256 + threadIdx.x) * 8;
  ushort8v o;
  if (isbf) {
    o = *(const ushort8v*)((const ushort_t*)X + i);
  } else {
    floatx4 f0 = *(const floatx4*)((const float*)X + i);
    floatx4 f1 = *(const floatx4*)((const float*)X + i + 4);
#pragma unroll
    for (int r = 0; r < 4; ++r) { o[r] = f2bf(f0[r]); o[4 + r] = f2bf(f1[r]); }
  }
  *(ushort8v*)(Xb + (size_t)z * MTOT * HID + i) = o;
}

// ---------- QKV GEMM: 128x128 tile, BK=64, global_load_lds(16B) staging ----------
// LDS layout [row][64] linear (global_load_lds needs linear dest); T2 swizzle is
// both-sides (G21): source col-block = (lane&7)^(lane>>3) at stage, read col-block
// cb^(row&7). Fragment/C-layouts identical to the proven reg-staged kernels.
__global__ __launch_bounds__(256) void gemm_qkv2(
    const ushort_t* __restrict__ Xb, const ushort_t* __restrict__ WtBase,
    const float* __restrict__ biasBase, ushort_t* __restrict__ YBase) {
  const int z = blockIdx.z;
  const ushort_t* X = Xb + (size_t)z * MTOT * HID;
  const ushort_t* Wt = WtBase + (size_t)z * HID * HID;
  const float* biasF = biasBase + (size_t)z * HID;
  ushort_t* Y = YBase + (size_t)z * MTOT * HID;

  const int tid = threadIdx.x;
  const int wid = tid >> 6, lane = tid & 63;
  const int id = lane & 15, quad = lane >> 4;
  const int wm = wid >> 1, wn = wid & 1;
  const int m0 = blockIdx.x * 128, n0 = blockIdx.y * 128;

  __shared__ ushort_t As[128 * 64];
  __shared__ ushort_t Bs[128 * 64];

  const int lrow = lane >> 3;                 // 0..7 within 8-row stripe
  const int scb  = (lane & 7) ^ lrow;         // inverse-swizzled source col-block

  floatx4 acc[4][4];
#pragma unroll
  for (int i = 0; i < 4; ++i)
#pragma unroll
    for (int j = 0; j < 4; ++j) acc[i][j] = (floatx4){0.f, 0.f, 0.f, 0.f};

  for (int k0 = 0; k0 < HID; k0 += 64) {
    __syncthreads();   // prev iter's ds_reads complete before overwrite
#pragma unroll
    for (int i = 0; i < 4; ++i) {
      int r = wid * 32 + i * 8 + lrow;
      gl_lds16(X + (long)(m0 + r) * HID + k0 + scb * 8, &As[(wid * 32 + i * 8) * 64]);
    }
#pragma unroll
    for (int i = 0; i < 4; ++i) {
      int r = wid * 32 + i * 8 + lrow;
      gl_lds16(Wt + (long)(n0 + r) * HID + k0 + scb * 8, &Bs[(wid * 32 + i * 8) * 64]);
    }
    __syncthreads();   // drains vmcnt -> tiles ready
#pragma unroll
    for (int kk = 0; kk < 64; kk += 32) {
      ushort8v af[4], bfv[4];
      const int cb = (kk >> 3) + quad;
#pragma unroll
      for (int ms = 0; ms < 4; ++ms) {
        int row = wm * 64 + ms * 16 + id;
        af[ms] = *(const ushort8v*)(&As[row * 64 + ((cb ^ (id & 7)) << 3)]);
      }
#pragma unroll
      for (int ns = 0; ns < 4; ++ns) {
        int row = wn * 64 + ns * 16 + id;
        bfv[ns] = *(const ushort8v*)(&Bs[row * 64 + ((cb ^ (id & 7)) << 3)]);
      }
#pragma unroll
      for (int ms = 0; ms < 4; ++ms)
#pragma unroll
        for (int ns = 0; ns < 4; ++ns)
          acc[ms][ns] = __builtin_amdgcn_mfma_f32_16x16x32_bf16(asbf(af[ms]), asbf(bfv[ns]), acc[ms][ns], 0, 0, 0);
    }
  }
#pragma unroll
  for (int ns = 0; ns < 4; ++ns) {
    int col = n0 + wn * 64 + ns * 16 + id;
    float bv = biasF[col];
#pragma unroll
    for (int ms = 0; ms < 4; ++ms) {
      int row0 = m0 + wm * 64 + ms * 16 + quad * 4;
#pragma unroll
      for (int r = 0; r < 4; ++r)
        Y[(long)(row0 + r) * HID + col] = f2bf(acc[ms][ns][r] + bv);
    }
  }
}

// ---------- out-proj GEMM: 64x128 tile, same staging/swizzle scheme ----------
__global__ __launch_bounds__(256) void gemm_out2(
    const ushort_t* __restrict__ X, const ushort_t* __restrict__ Wt,
    const float* __restrict__ biasF, void* __restrict__ out,
    const int* __restrict__ flag) {
  const int isbf = flag[0];
  const int tid = threadIdx.x;
  const int wid = tid >> 6, lane = tid & 63;
  const int id = lane & 15, quad = lane >> 4;
  const int wm = wid >> 1, wn = wid & 1;
  const int m0 = blockIdx.x * 64, n0 = blockIdx.y * 128;

  __shared__ ushort_t As[64 * 64];
  __shared__ ushort_t Bs[128 * 64];

  const int lrow = lane >> 3;
  const int scb  = (lane & 7) ^ lrow;

  floatx4 acc[2][4];
#pragma unroll
  for (int i = 0; i < 2; ++i)
#pragma unroll
    for (int j = 0; j < 4; ++j) acc[i][j] = (floatx4){0.f, 0.f, 0.f, 0.f};

  for (int k0 = 0; k0 < HID; k0 += 64) {
    __syncthreads();
#pragma unroll
    for (int i = 0; i < 2; ++i) {
      int r = wid * 16 + i * 8 + lrow;
      gl_lds16(X + (long)(m0 + r) * HID + k0 + scb * 8, &As[(wid * 16 + i * 8) * 64]);
    }
#pragma unroll
    for (int i = 0; i < 4; ++i) {
      int r = wid * 32 + i * 8 + lrow;
      gl_lds16(Wt + (long)(n0 + r) * HID + k0 + scb * 8, &Bs[(wid * 32 + i * 8) * 64]);
    }
    __syncthreads();
#pragma unroll
    for (int kk = 0; kk < 64; kk += 32) {
      ushort8v af[2], bfv[4];
      const int cb = (kk >> 3) + quad;
#pragma unroll
      for (int ms = 0; ms < 2; ++ms) {
        int row = wm * 32 + ms * 16 + id;
        af[ms] = *(const ushort8v*)(&As[row * 64 + ((cb ^ (id & 7)) << 3)]);
      }
#pragma unroll
      for (int ns = 0; ns < 4; ++ns) {
        int row = wn * 64 + ns * 16 + id;
        bfv[ns] = *(const ushort8v*)(&Bs[row * 64 + ((cb ^ (id & 7)) << 3)]);
      }
#pragma unroll
      for (int ms = 0; ms < 2; ++ms)
#pragma unroll
        for (int ns = 0; ns < 4; ++ns)
          acc[ms][ns] = __builtin_amdgcn_mfma_f32_16x16x32_bf16(asbf(af[ms]), asbf(bfv[ns]), acc[ms][ns], 0, 0, 0);
    }
  }
#pragma unroll
  for (int ns = 0; ns < 4; ++ns) {
    int col = n0 + wn * 64 + ns * 16 + id;
    float bv = biasF[col];
#pragma unroll
    for (int ms = 0; ms < 2; ++ms) {
      int row0 = m0 + wm * 32 + ms * 16 + quad * 4;
      if (isbf) {
        ushort_t* o = (ushort_t*)out;
#pragma unroll
        for (int r = 0; r < 4; ++r) o[(long)(row0 + r) * HID + col] = f2bf(acc[ms][ns][r] + bv);
      } else {
        float* o = (float*)out;
#pragma unroll
        for (int r = 0; r < 4; ++r) o[(long)(row0 + r) * HID + col] = acc[ms][ns][r] + bv;
      }
    }
  }
}

// ---------- flash attention — exp2 via v_exp_f32, v_perm V-pack, treed rs ----------
__global__ __launch_bounds__(256) void flash_attn(
    const ushort_t* __restrict__ Q, const ushort_t* __restrict__ K,
    const ushort_t* __restrict__ V, const float* __restrict__ mb,
    ushort_t* __restrict__ ctx) {
  const int qblk = blockIdx.x, h = blockIdx.y, b = blockIdx.z;
  const int tid = threadIdx.x;
  const int wid = tid >> 6, lane = tid & 63;
  const int id = lane & 15, quad = lane >> 4;

  __shared__ ushort_t Kt[64 * 72];       // [key][d] stride 72
  __shared__ ushort_t Vt[64 * 72];       // [d][key] stride 72 (transposed)
  __shared__ ushort_t Pl[4][32 * 72];    // per-wave P as [q][key] stride 72

  const ushort_t* Qb = Q + (long)(b * SEQ + qblk * 128 + wid * 32) * HID + h * HD;
  const ushort_t* Kb = K + (long)(b * SEQ) * HID + h * HD;
  const ushort_t* Vb = V + (long)(b * SEQ) * HID + h * HD;
  const float* mrow = mb + b * SEQ;

  ushort8v qf[2][2];
#pragma unroll
  for (int qs = 0; qs < 2; ++qs)
#pragma unroll
    for (int kh = 0; kh < 2; ++kh)
      qf[qs][kh] = *(const ushort8v*)(Qb + (qs * 16 + id) * HID + kh * 32 + quad * 8);

  floatx4 o[4][2];
  float m_i[2] = {-1e30f, -1e30f}, l_i[2] = {0.f, 0.f};
#pragma unroll
  for (int dg = 0; dg < 4; ++dg) { o[dg][0] = (floatx4){0,0,0,0}; o[dg][1] = (floatx4){0,0,0,0}; }

  const int skey = tid >> 2;             // K staging: 0..63
  const int sdc  = (tid & 3) * 16;       // K staging: 0,16,32,48
  const int vkp  = (tid & 31) * 2;       // V staging: key pair 0..62
  const int vdc  = (tid >> 5) * 8;       // V staging: d col 0..56

  // prefetch tile 0 into registers
  ushort8v k0v, k1v, v0v, v1v;
  {
    const ushort_t* kpp = Kb + (long)skey * HID + sdc;
    k0v = *(const ushort8v*)(kpp);
    k1v = *(const ushort8v*)(kpp + 8);
    const ushort_t* vp0 = Vb + (long)vkp * HID + vdc;
    v0v = *(const ushort8v*)(vp0);
    v1v = *(const ushort8v*)(vp0 + HID);
  }

  for (int kb = 0; kb < SEQ / 64; ++kb) {
    // ---- write prefetched regs to LDS (K row-major, V transposed via v_perm) ----
    *(ushort8v*)(&Kt[skey * 72 + sdc])     = k0v;
    *(ushort8v*)(&Kt[skey * 72 + sdc + 8]) = k1v;
    {
      uintx4 a = __builtin_bit_cast(uintx4, v0v);
      uintx4 bq = __builtin_bit_cast(uintx4, v1v);
#pragma unroll
      for (int j = 0; j < 4; ++j) {
        unsigned int d0 = __builtin_amdgcn_perm(bq[j], a[j], 0x05040100u); // [B0 A0]
        unsigned int d1 = __builtin_amdgcn_perm(bq[j], a[j], 0x07060302u); // [B1 A1]
        *(unsigned int*)(&Vt[(vdc + 2 * j) * 72 + vkp])     = d0;
        *(unsigned int*)(&Vt[(vdc + 2 * j + 1) * 72 + vkp]) = d1;
      }
    }
    __syncthreads();

    // ---- issue next-tile global loads; latency hides under this tile's compute ----
    if (kb + 1 < SEQ / 64) {
      const ushort_t* kpp = Kb + (long)((kb + 1) * 64 + skey) * HID + sdc;
      k0v = *(const ushort8v*)(kpp);
      k1v = *(const ushort8v*)(kpp + 8);
      const ushort_t* vp0 = Vb + (long)((kb + 1) * 64 + vkp) * HID + vdc;
      v0v = *(const ushort8v*)(vp0);
      v1v = *(const ushort8v*)(vp0 + HID);
    }

    floatx4 st[2][4];
#pragma unroll
    for (int ks = 0; ks < 4; ++ks) {
      ushort8v kf0 = *(const ushort8v*)(&Kt[(ks * 16 + id) * 72 + quad * 8]);
      ushort8v kf1 = *(const ushort8v*)(&Kt[(ks * 16 + id) * 72 + 32 + quad * 8]);
#pragma unroll
      for (int qs = 0; qs < 2; ++qs) {
        floatx4 a = (floatx4){0,0,0,0};
        a = __builtin_amdgcn_mfma_f32_16x16x32_bf16(asbf(kf0), asbf(qf[qs][0]), a, 0, 0, 0);
        a = __builtin_amdgcn_mfma_f32_16x16x32_bf16(asbf(kf1), asbf(qf[qs][1]), a, 0, 0, 0);
        st[qs][ks] = a;
      }
    }
    // ---- scale (exp2 domain) + additive mask bias in one fma ----
#pragma unroll
    for (int ks = 0; ks < 4; ++ks) {
      floatx4 mbv = *(const floatx4*)(mrow + kb * 64 + ks * 16 + quad * 4);
#pragma unroll
      for (int r = 0; r < 4; ++r) {
        st[0][ks][r] = fmaf(st[0][ks][r], SC_LOG2E, mbv[r]);
        st[1][ks][r] = fmaf(st[1][ks][r], SC_LOG2E, mbv[r]);
      }
    }
#pragma unroll
    for (int qs = 0; qs < 2; ++qs) {
      float a0 = max3f(st[qs][0][0], st[qs][0][1], st[qs][0][2]);
      float a1 = max3f(st[qs][0][3], st[qs][1][0], st[qs][1][1]);
      float a2 = max3f(st[qs][1][2], st[qs][1][3], st[qs][2][0]);
      float a3 = max3f(st[qs][2][1], st[qs][2][2], st[qs][2][3]);
      float a4 = max3f(st[qs][3][0], st[qs][3][1], st[qs][3][2]);
      float mx = max3f(a0, a1, st[qs][3][3]);
      float mz = max3f(a2, a3, a4);
      mx = fmaxf(mx, mz);
      mx = fmaxf(mx, __shfl_xor(mx, 16));
      mx = fmaxf(mx, __shfl_xor(mx, 32));
      // defer-max (T13): skip O/l rescale while max growth <= 8 (log2 units)
      if (!__all(mx - m_i[qs] <= 8.f)) {
        float mnew = fmaxf(m_i[qs], mx);
        float alpha = fexp2(m_i[qs] - mnew);
        m_i[qs] = mnew;
        l_i[qs] *= alpha;
#pragma unroll
        for (int dg = 0; dg < 4; ++dg) o[dg][qs] *= alpha;
      }
      float mcur = m_i[qs];
      floatx4 rsv = (floatx4){0.f, 0.f, 0.f, 0.f};   // 4 independent chains
#pragma unroll
      for (int ks = 0; ks < 4; ++ks) {
        ushort4v pk;
#pragma unroll
        for (int r = 0; r < 4; ++r) {
          float p = fexp2(st[qs][ks][r] - mcur);
          rsv[r] += p;
          pk[r] = f2bf(p);
        }
        *(ushort4v*)(&Pl[wid][(qs * 16 + id) * 72 + ks * 16 + quad * 4]) = pk;
      }
      float rs = (rsv[0] + rsv[1]) + (rsv[2] + rsv[3]);
      rs += __shfl_xor(rs, 16);
      rs += __shfl_xor(rs, 32);
      l_i[qs] += rs;
    }
    // Pl is per-wave: intra-wave lgkmcnt ordering suffices, no barrier.

#pragma unroll
    for (int kc = 0; kc < 2; ++kc) {
      ushort8v pf0 = *(const ushort8v*)(&Pl[wid][(0 * 16 + id) * 72 + kc * 32 + quad * 8]);
      ushort8v pf1 = *(const ushort8v*)(&Pl[wid][(1 * 16 + id) * 72 + kc * 32 + quad * 8]);
#pragma unroll
      for (int dg = 0; dg < 4; ++dg) {
        ushort8v vf = *(const ushort8v*)(&Vt[(dg * 16 + id) * 72 + kc * 32 + quad * 8]);
        o[dg][0] = __builtin_amdgcn_mfma_f32_16x16x32_bf16(asbf(vf), asbf(pf0), o[dg][0], 0, 0, 0);
        o[dg][1] = __builtin_amdgcn_mfma_f32_16x16x32_bf16(asbf(vf), asbf(pf1), o[dg][1], 0, 0, 0);
      }
    }
    __syncthreads();   // all waves done reading Kt/Vt before next-tile staging
  }

#pragma unroll
  for (int qs = 0; qs < 2; ++qs) {
    float inv = 1.0f / l_i[qs];
    long qrow = (long)(b * SEQ + qblk * 128 + wid * 32 + qs * 16 + id);
#pragma unroll
    for (int dg = 0; dg < 4; ++dg) {
      ushort4v pk;
#pragma unroll
      for (int r = 0; r < 4; ++r) pk[r] = f2bf(o[dg][qs][r] * inv);
      *(ushort4v*)(&ctx[qrow * HID + h * HD + dg * 16 + quad * 4]) = pk;
    }
  }
}

extern "C" void kernel_launch(void* const* d_in, const int* in_sizes, int n_in,
                              void* d_out, int out_size, void* d_ws, size_t ws_size,
                              hipStream_t stream) {
  const void* values = d_in[0];
  const void* keys   = d_in[1];
  const void* query  = d_in[2];
  const int*  mask   = (const int*)d_in[3];
  const void* Wq = d_in[4];  const void* bq = d_in[5];
  const void* Wk = d_in[6];  const void* bk = d_in[7];
  const void* Wv = d_in[8];  const void* bv = d_in[9];
  const void* Wo = d_in[10]; const void* bo = d_in[11];

  ushort_t* ws = (ushort_t*)d_ws;
  const size_t NEL = (size_t)MTOT * HID;
  ushort_t* Qp  = ws;                       // Qp/Kp/Vp contiguous
  ushort_t* Kp  = ws + NEL;
  ushort_t* Vp  = ws + 2 * NEL;
  ushort_t* Cp  = ws + 3 * NEL;
  ushort_t* Xb  = ws + 4 * NEL;             // bf16 query/keys/values, 3*NEL
  ushort_t* WqT = ws + 7 * NEL;             // WqT/WkT/WvT contiguous
  ushort_t* WkT = WqT + (size_t)HID * HID;
  ushort_t* WvT = WkT + (size_t)HID * HID;
  ushort_t* WoT = WvT + (size_t)HID * HID;
  float* biasF  = (float*)(WoT + (size_t)HID * HID);   // q,k,v,o contiguous
  float* mbias  = biasF + 4 * HID;                     // BATCH*SEQ floats
  int* flag     = (int*)(mbias + (size_t)BATCH * SEQ);

  detect_dtype<<<1, 64, 0, stream>>>((const unsigned int*)query, flag);
  prep_w<<<dim3(1024, 4), 256, 0, stream>>>(Wq, Wk, Wv, Wo, WqT, WkT, WvT, WoT, flag);
  prep_b<<<8, 256, 0, stream>>>(bq, bk, bv, bo, biasF, flag);
  prep_mask<<<MTOT / 256, 256, 0, stream>>>(mask, mbias);
  prep_x<<<dim3(MTOT * HID / (256 * 8), 3), 256, 0, stream>>>(query, keys, values, Xb, flag);

  // QKV: grid (64, 4, 3) = 768 blocks (3 blocks/CU), 128x128 tile, gl_lds staging
  gemm_qkv2<<<dim3(MTOT / 128, HID / 128, 3), 256, 0, stream>>>(Xb, WqT, biasF, Qp);

  flash_attn<<<dim3(SEQ / 128, NH, BATCH), 256, 0, stream>>>(Qp, Kp, Vp, mbias, Cp);

  gemm_out2<<<dim3(MTOT / 64, HID / 128), 256, 0, stream>>>(
      Cp, WoT, biasF + 3 * HID, d_out, flag);
}